// Round 1
// baseline (247.060 us; speedup 1.0000x reference)
//
#include <hip/hip_runtime.h>
#include <hip/hip_bf16.h>

// Isokawa quaternion layer as bf16-MFMA GEMM:
//   out[b, n*4+oc] = sigmoid( sum_k x[b,k] * C[k, n*4+oc] - theta[n*4+oc] )
// B=131072 rows, K=256, N=256. Memory-bound: 134 MB in + 134 MB out.
//
// R3: pipelined multi-tile blocks.
//  - TPB=4 tiles (64 rows each) per block; breg/theta loaded once per block.
//  - x prefetch for tile t+1 issued inside tile t's staging loop; barriers are
//    raw lgkmcnt(0)+s_barrier so prefetch loads stay in flight (no vmcnt drain).
//  - MFMA operands SWAPPED (breg as A, x-frag as B) -> D is transposed:
//    lane&15 = batch row, quad*4+reg = 4 consecutive n-cols -> float4 stores.
//  - sigmoid uses v_rcp_f32 (fast) instead of full IEEE divide.

typedef __bf16 bf16_t;
typedef bf16_t bf16x8 __attribute__((ext_vector_type(8)));
typedef bf16_t bf16x4v __attribute__((ext_vector_type(4)));
typedef float f32x4 __attribute__((ext_vector_type(4)));

#define B_TOTAL 131072
#define KDIM 256
#define NDIM 256
#define ROWS 64          // batch rows per tile
#define THREADS 512      // 8 waves; wave w owns cols [w*32, w*32+32)
#define LDS_STRIDE 264   // bf16 elems per row: 256 + 8 pad (row stride = 4 banks mod 32 -> 2-way, free)
#define TPB 4            // tiles per block
#define GRID (B_TOTAL / (ROWS * TPB))   // 512 blocks

// ---------------------------------------------------------------------------
// Kernel 1: build coefficient matrix in MFMA B-fragment order (bf16, in d_ws).
//   coef_frag[((nt*8 + ks)*64 + lane)*8 + j] = Bmat[k][col]
//     col = nt*16 + (lane&15),  k = ks*32 + (lane>>4)*8 + j
// Bmat[k][col]: col = n*4+oc, k = m*4+ic,
//   value = sign[oc][ic] * W[n, m, widx[oc][ic]]  (Hamilton, W on the left)
// ---------------------------------------------------------------------------
__global__ void coef_kernel(const float* __restrict__ W, bf16_t* __restrict__ coef) {
    const int widx[4][4] = {{0,1,2,3},{1,0,3,2},{2,3,0,1},{3,2,1,0}};
    const float sgn[4][4] = {{1.f,-1.f,-1.f,-1.f},
                             {1.f, 1.f,-1.f, 1.f},
                             {1.f, 1.f, 1.f,-1.f},
                             {1.f,-1.f, 1.f, 1.f}};
    int F = blockIdx.x * blockDim.x + threadIdx.x;   // 0..65535, one elem each
    int j    = F & 7;
    int lane = (F >> 3) & 63;
    int ks   = (F >> 9) & 7;
    int nt   = F >> 12;
    int col  = nt * 16 + (lane & 15);
    int k    = ks * 32 + (lane >> 4) * 8 + j;
    int n = col >> 2, oc = col & 3;
    int m = k >> 2,   ic = k & 3;
    coef[F] = (bf16_t)(sgn[oc][ic] * W[n * 256 + m * 4 + widx[oc][ic]]);
}

// ---------------------------------------------------------------------------
// Kernel 2: main GEMM, pipelined over TPB tiles.
// MFMA 16x16x32 bf16 layouts (m89/m120-verified):
//   A-op: lane holds A[m=lane&15][k=(lane>>4)*8 + j]
//   B-op: lane holds B[k=(lane>>4)*8 + j][n=lane&15]
//   C/D : col=lane&15, row=(lane>>4)*4 + reg
// We compute D' = mfma(coefFrag, xFrag): coefFrag-as-A = coef^T (n x k),
// xFrag-as-B = x^T (k x row)  =>  D'[n][row]; lane&15 = batch row,
// quad*4+reg = n-col => each lane holds 4 CONSECUTIVE output cols (float4 store).
// ---------------------------------------------------------------------------
__global__ __launch_bounds__(THREADS, 2)
void main_kernel(const float* __restrict__ x, const bf16x8* __restrict__ coef,
                 const float* __restrict__ theta, float* __restrict__ out) {
    __shared__ __align__(16) bf16_t xs[ROWS * LDS_STRIDE];

    const int tid  = threadIdx.x;
    const int wave = tid >> 6, lane = tid & 63;
    const int l15  = lane & 15, quad = lane >> 4;
    const long tile0 = (long)blockIdx.x * TPB;
    const float4* xbase = (const float4*)x;

    // --- issue x loads for tile 0 FIRST (HBM, longest latency), coalesced float4
    float4 v[8];
    {
        const float4* xp = xbase + tile0 * (ROWS * KDIM / 4);
#pragma unroll
        for (int i = 0; i < 8; i++) v[i] = xp[tid + THREADS * i];
    }

    // --- this wave's entire B slice into registers (L2 hits), reused for all tiles
    bf16x8 breg[2][8];
#pragma unroll
    for (int ct = 0; ct < 2; ct++)
#pragma unroll
        for (int ks = 0; ks < 8; ks++)
            breg[ct][ks] = coef[((wave * 2 + ct) * 8 + ks) * 64 + lane];

    // --- theta for this lane's 2x4 output columns (swapped layout), float4 loads
    f32x4 th4[2];
#pragma unroll
    for (int ct = 0; ct < 2; ct++)
        th4[ct] = *(const f32x4*)&theta[wave * 32 + ct * 16 + quad * 4];

#pragma unroll
    for (int t = 0; t < TPB; t++) {
        // --- stage tile t (regs -> bf16 LDS); re-issue v[i] for tile t+1 as soon
        //     as its old value is consumed -> loads in flight across the barrier
        const float4* xq = xbase + (tile0 + t + 1) * (ROWS * KDIM / 4);
#pragma unroll
        for (int i = 0; i < 8; i++) {
            int f = tid + THREADS * i;          // float4 index in 64x256 tile
            int r = f >> 6;                     // row (64 float4 per row)
            int c = (f & 63) * 4;               // k offset
            bf16x4v w;
            w.x = (bf16_t)v[i].x; w.y = (bf16_t)v[i].y;
            w.z = (bf16_t)v[i].z; w.w = (bf16_t)v[i].w;
            *(bf16x4v*)&xs[r * LDS_STRIDE + c] = w;
            if (t + 1 < TPB) v[i] = xq[tid + THREADS * i];   // prefetch next tile
        }

        // barrier WITHOUT vmcnt drain (prefetch + prior stores stay in flight)
        asm volatile("s_waitcnt lgkmcnt(0)" ::: "memory");
        __builtin_amdgcn_s_barrier();

        f32x4 acc[4][2];
#pragma unroll
        for (int rt = 0; rt < 4; rt++)
#pragma unroll
            for (int ct = 0; ct < 2; ct++) acc[rt][ct] = (f32x4)(0.f);

        // --- K-loop: pure LDS reads + MFMA (operands swapped), fully unrolled
#pragma unroll
        for (int ks = 0; ks < 8; ks++) {
            bf16x8 a[4];
#pragma unroll
            for (int rt = 0; rt < 4; rt++)
                a[rt] = *(const bf16x8*)&xs[(rt * 16 + l15) * LDS_STRIDE + ks * 32 + quad * 8];
#pragma unroll
            for (int rt = 0; rt < 4; rt++)
#pragma unroll
                for (int ct = 0; ct < 2; ct++)
                    acc[rt][ct] = __builtin_amdgcn_mfma_f32_16x16x32_bf16(
                        breg[ct][ks], a[rt], acc[rt][ct], 0, 0, 0);
        }

        // all LDS reads of this tile consumed; release buffer for next iteration
        asm volatile("s_waitcnt lgkmcnt(0)" ::: "memory");
        __builtin_amdgcn_s_barrier();

        // --- epilogue: bias + sigmoid (fast rcp), float4 stores; registers only,
        //     overlaps other waves already staging tile t+1
        const long row0 = (tile0 + t) * ROWS;
#pragma unroll
        for (int rt = 0; rt < 4; rt++) {
            long row = row0 + rt * 16 + l15;
#pragma unroll
            for (int ct = 0; ct < 2; ct++) {
                f32x4 y;
#pragma unroll
                for (int j = 0; j < 4; j++) {
                    float s = acc[rt][ct][j] - th4[ct][j];
                    y[j] = __builtin_amdgcn_rcpf(1.0f + __expf(-s));
                }
                *(f32x4*)&out[row * NDIM + wave * 32 + ct * 16 + quad * 4] = y;
            }
        }
    }
}

extern "C" void kernel_launch(void* const* d_in, const int* in_sizes, int n_in,
                              void* d_out, int out_size, void* d_ws, size_t ws_size,
                              hipStream_t stream) {
    const float* x     = (const float*)d_in[0];   // (131072, 64, 4) fp32
    const float* W     = (const float*)d_in[1];   // (64, 64, 4) fp32
    const float* theta = (const float*)d_in[2];   // (64, 4) fp32
    float* out = (float*)d_out;                   // (131072, 64, 4) fp32
    bf16_t* coef = (bf16_t*)d_ws;                 // 65536 bf16 = 128 KB

    if (ws_size < 65536 * sizeof(bf16_t)) return;

    coef_kernel<<<256, 256, 0, stream>>>(W, coef);
    main_kernel<<<GRID, THREADS, 0, stream>>>(
        x, (const bf16x8*)coef, theta, out);
}